// Round 1
// baseline (199.250 us; speedup 1.0000x reference)
//
#include <hip/hip_runtime.h>
#include <math.h>

#define KBINS 128
#define NTHR  256

// ---------------------------------------------------------------------------
// Main pass: one wave per row. Lane l owns columns (2l, 2l+1).
// Per block: partial per-column sum-exp (masked by label>=col), partial event
// histogram, partial S1 = sum ev*own, partial event count.
// Partials written coalesced to global: part[block][col].
// ---------------------------------------------------------------------------
__global__ __launch_bounds__(NTHR) void cox_main(
    const float* __restrict__ logits, const int* __restrict__ labels,
    const int* __restrict__ events, float* __restrict__ part_denom,
    int* __restrict__ part_hist, float* __restrict__ part_s1,
    int* __restrict__ part_ev, int B)
{
    __shared__ float partLds[4][KBINS];
    __shared__ int   hist[KBINS];
    __shared__ float s1w[4];
    __shared__ int   evw[4];

    const int t    = threadIdx.x;
    const int wave = t >> 6;
    const int lane = t & 63;
    if (t < KBINS) hist[t] = 0;
    __syncthreads();

    const int c0 = lane << 1;          // this lane's even column
    float sa = 0.f, sb = 0.f;          // running sum-exp for cols c0, c0+1
    float accOwn = 0.f;
    int   accEv  = 0;

    const int stride = gridDim.x * 4;
    for (int r = blockIdx.x * 4 + wave; r < B; r += stride) {
        const float2 v = *reinterpret_cast<const float2*>(
            logits + (size_t)r * KBINS + c0);
        const int lab = labels[r];
        const int ev  = events[r];
        const float e0 = __expf(v.x);
        const float e1 = __expf(v.y);
        if (lab >= c0) sa += e0;       // label >= c0
        if (lab >  c0) sb += e1;       // label >= c0+1
        if ((lab >> 1) == lane) {      // exactly one lane per row
            if (ev) {
                accOwn += (lab & 1) ? v.y : v.x;
                atomicAdd(&hist[lab], 1);
            }
        }
        if (lane == 0) accEv += ev;
    }

    // wave-level reduce of accOwn (accEv only lives on lane 0)
    for (int off = 32; off; off >>= 1) {
        accOwn += __shfl_down(accOwn, off);
    }
    if (lane == 0) { s1w[wave] = accOwn; evw[wave] = accEv; }
    partLds[wave][c0]     = sa;
    partLds[wave][c0 + 1] = sb;
    __syncthreads();

    if (t < KBINS) {
        const int o = blockIdx.x * KBINS + t;
        part_denom[o] = partLds[0][t] + partLds[1][t] + partLds[2][t] + partLds[3][t];
        part_hist[o]  = hist[t];
    }
    if (t == 0) {
        part_s1[blockIdx.x] = s1w[0] + s1w[1] + s1w[2] + s1w[3];
        part_ev[blockIdx.x] = evw[0] + evw[1] + evw[2] + evw[3];
    }
}

// ---------------------------------------------------------------------------
// Reduce partials per column: term[k] = n_ev[k]>0 ? n_ev[k]*log(denom[k]) : 0
// One block per column.
// ---------------------------------------------------------------------------
__global__ __launch_bounds__(256) void cox_fin1(
    const float* __restrict__ part_denom, const int* __restrict__ part_hist,
    double* __restrict__ term, int nblk)
{
    const int k = blockIdx.x;
    const int t = threadIdx.x;
    double d = 0.0;
    int    h = 0;
    for (int b = t; b < nblk; b += 256) {
        d += (double)part_denom[(size_t)b * KBINS + k];
        h += part_hist[(size_t)b * KBINS + k];
    }
    __shared__ double ds[256];
    __shared__ int    hs[256];
    ds[t] = d; hs[t] = h;
    __syncthreads();
    for (int off = 128; off; off >>= 1) {
        if (t < off) { ds[t] += ds[t + off]; hs[t] += hs[t + off]; }
        __syncthreads();
    }
    if (t == 0) term[k] = (hs[0] > 0) ? (double)hs[0] * log(ds[0]) : 0.0;
}

// ---------------------------------------------------------------------------
// Final: loss = (S2 - S1) / max(n_total, 1)
// ---------------------------------------------------------------------------
__global__ __launch_bounds__(256) void cox_fin2(
    const double* __restrict__ term, const float* __restrict__ part_s1,
    const int* __restrict__ part_ev, float* __restrict__ out, int nblk)
{
    const int t = threadIdx.x;
    double s2 = (t < KBINS) ? term[t] : 0.0;
    double s1 = 0.0;
    int    ne = 0;
    for (int b = t; b < nblk; b += 256) {
        s1 += (double)part_s1[b];
        ne += part_ev[b];
    }
    __shared__ double a[256];
    __shared__ double c[256];
    __shared__ int    e[256];
    a[t] = s2; c[t] = s1; e[t] = ne;
    __syncthreads();
    for (int off = 128; off; off >>= 1) {
        if (t < off) { a[t] += a[t + off]; c[t] += c[t + off]; e[t] += e[t + off]; }
        __syncthreads();
    }
    if (t == 0) {
        double ntot = (double)(e[0] > 1 ? e[0] : 1);
        out[0] = (float)((a[0] - c[0]) / ntot);
    }
}

// ---------------------------------------------------------------------------
extern "C" void kernel_launch(void* const* d_in, const int* in_sizes, int n_in,
                              void* d_out, int out_size, void* d_ws, size_t ws_size,
                              hipStream_t stream) {
    const float* logits = (const float*)d_in[0];
    const int*   labels = (const int*)d_in[1];
    const int*   events = (const int*)d_in[2];
    const int B = in_sizes[1];

    // pick largest block count (<=2048) whose partials fit in ws
    int nblk = 2048;
    auto need = [](size_t nb) {
        return nb * KBINS * 4            // part_denom (float)
             + nb * KBINS * 4            // part_hist (int)
             + nb * 4                    // part_s1
             + nb * 4                    // part_ev
             + KBINS * 8 + 64;           // term (double) + slack
    };
    while (nblk > 64 && need((size_t)nblk) > ws_size) nblk >>= 1;

    char* ws = (char*)d_ws;
    float*  part_denom = (float*)ws;
    int*    part_hist  = (int*)(ws + (size_t)nblk * KBINS * 4);
    float*  part_s1    = (float*)(ws + (size_t)2 * nblk * KBINS * 4);
    int*    part_ev    = (int*)(ws + (size_t)2 * nblk * KBINS * 4 + (size_t)nblk * 4);
    double* term       = (double*)(ws + (size_t)2 * nblk * KBINS * 4 + (size_t)2 * nblk * 4);

    cox_main<<<nblk, NTHR, 0, stream>>>(logits, labels, events,
                                        part_denom, part_hist, part_s1, part_ev, B);
    cox_fin1<<<KBINS, 256, 0, stream>>>(part_denom, part_hist, term, nblk);
    cox_fin2<<<1, 256, 0, stream>>>(term, part_s1, part_ev, (float*)d_out, nblk);
}